// Round 8
// baseline (127.647 us; speedup 1.0000x reference)
//
#include <hip/hip_runtime.h>
#include <math.h>

#define P 7
#define SCALE 0.125f
#define BB 4
#define CC 256
#define HH 128
#define WW 128
#define KK 512
#define NBIN 49
#define GPB 13            // bin-groups per ROI (4 bins each, 13*4 >= 49)
#define NXCD 8

__device__ __forceinline__ unsigned short f32_to_bf16_rne(float f) {
    unsigned int u = __float_as_uint(f);
    u += 0x7FFFu + ((u >> 16) & 1u);
    return (unsigned short)(u >> 16);
}

// Order-preserving bf16 -> u16 key. key 0 reserved = "empty/masked".
__device__ __forceinline__ unsigned short bf16_key(unsigned short b) {
    return (b & 0x8000u) ? (unsigned short)(~b) : (unsigned short)(b | 0x8000u);
}

__device__ __forceinline__ unsigned int pkmax_u16(unsigned int a, unsigned int b) {
    unsigned int d;
    asm("v_pk_max_u16 %0, %1, %2" : "=v"(d) : "v"(a), "v"(b));
    return d;
}

// ---- Transpose+convert: [B,C,H,W] f32 -> [B,H*W,C] packed u16 keys ----
__global__ __launch_bounds__(1024) void transpose_cvt(
    const float* __restrict__ in, unsigned short* __restrict__ out)
{
    __shared__ float tile[64][65];    // tile[channel][pixel]
    const int p0 = blockIdx.x * 64;
    const int c0 = blockIdx.y * 64;
    const int b  = blockIdx.z;
    const int tx = threadIdx.x;       // 0..63
    const int ty = threadIdx.y;       // 0..15

    const float* src = in + (size_t)b * CC * (HH * WW);
#pragma unroll
    for (int j = 0; j < 64; j += 16)
        tile[ty + j][tx] =
            __builtin_nontemporal_load(&src[(size_t)(c0 + ty + j) * (HH * WW) + p0 + tx]);
    __syncthreads();

    unsigned int* dst = (unsigned int*)(out + (size_t)b * (HH * WW) * CC);
    const int t = ty * 64 + tx;
#pragma unroll
    for (int i = 0; i < 2; ++i) {
        const int flat = i * 1024 + t;
        const int px = flat >> 5;
        const int cp = flat & 31;
        const unsigned int lo = bf16_key(f32_to_bf16_rne(tile[cp * 2][px]));
        const unsigned int hi = bf16_key(f32_to_bf16_rne(tile[cp * 2 + 1][px]));
        dst[((size_t)(p0 + px) * CC + c0) / 2 + cp] = lo | (hi << 16);
    }
}

// ---- Mask -> bitmask: [K,H,W] f32 -> [K,H] 2xu64 (bit w = mask>0.5) ----
__global__ __launch_bounds__(256) void mask_bits(
    const float* __restrict__ masks, unsigned long long* __restrict__ mbits)
{
    const int wv   = threadIdx.x >> 6;            // wave in block
    const int lane = threadIdx.x & 63;
    const int row  = blockIdx.x * 4 + wv;         // 0 .. K*H-1
    const float* mr = masks + (size_t)row * WW;
    const unsigned long long b0 = __ballot(mr[lane] > 0.5f);
    const unsigned long long b1 = __ballot(mr[64 + lane] > 0.5f);
    if (lane == 0) {
        mbits[(size_t)row * 2]     = b0;
        mbits[(size_t)row * 2 + 1] = b1;
    }
}

// ---- Pool: one wave per bin, 8-px chunks, bitmask predication ----
__global__ __launch_bounds__(256) void pool_key(
    const unsigned short* __restrict__ fT,          // [B,HW,C] u16 keys
    const float* __restrict__ rois,                 // [K,5]
    const unsigned long long* __restrict__ mbits,   // [K,H,2]
    float* __restrict__ out)                        // [K,C,P,P]
{
    // XCD-aware swizzle: all GPB blocks of ROI k land on XCD k%8
    const int pid = blockIdx.x;
    const int x   = pid & (NXCD - 1);
    const int t   = pid >> 3;
    const int g   = t % GPB;
    const int q   = t / GPB;
    const int k   = q * NXCD + x;

    const int wv   = threadIdx.x >> 6;
    const int lane = threadIdx.x & 63;
    const int bi   = g * 4 + wv;
    if (bi >= NBIN) return;                 // wave-uniform
    const int ph = bi / P;
    const int pw = bi % P;

    const int half = lane >> 5;             // even/odd pixel of each pair
    const int c4   = (lane & 31) * 4;       // uint offset: 8 channels

    const float* roi = rois + k * 5;
    const int b  = (int)roi[0];
    const int sw = (int)rintf(roi[1] * SCALE);
    const int sh = (int)rintf(roi[2] * SCALE);
    const int ew = (int)rintf(roi[3] * SCALE);
    const int eh = (int)rintf(roi[4] * SCALE);
    const int roi_w = max(ew - sw + 1, 1);
    const int roi_h = max(eh - sh + 1, 1);

    const int hs = min(max((ph * roi_h) / P + sh, 0), HH);
    const int he = min(max(((ph + 1) * roi_h + P - 1) / P + sh, 0), HH);
    const int wl = min(max((pw * roi_w) / P + sw, 0), WW);
    const int wr = min(max(((pw + 1) * roi_w + P - 1) / P + sw, 0), WW);

    const unsigned int* fb =
        (const unsigned int*)(fT + (size_t)b * (HH * WW) * CC) + c4;
    const unsigned long long* mrow = mbits + (size_t)k * HH * 2;

    unsigned int a0 = 0, a1 = 0, a2 = 0, a3 = 0;   // packed key accumulators

#pragma unroll 2
    for (int h = hs; h < he; ++h) {
        const unsigned long long lo = mrow[h * 2];
        const unsigned long long hi = mrow[h * 2 + 1];
        const unsigned int* frow = fb + (size_t)h * WW * (CC / 2);
        for (int w0 = wl; w0 < wr; w0 += 8) {
            // wave-uniform 8-bit mask chunk for pixels w0..w0+7 (SALU)
            unsigned long long sh64;
            if (w0 >= 64)      sh64 = hi >> (w0 - 64);
            else if (w0 == 0)  sh64 = lo;
            else               sh64 = (lo >> w0) | (hi << (64 - w0));
            unsigned int chunk = (unsigned int)(sh64 & 0xFFu);
            const int n = wr - w0;                     // valid pixel count
            chunk &= (n >= 8) ? 0xFFu : ((1u << n) - 1u);

            uint4 kv[4];
#pragma unroll
            for (int p = 0; p < 4; ++p) {
                const int wc = min(w0 + p * 2 + half, wr - 1);
                kv[p] = *(const uint4*)(frow + (size_t)wc * (CC / 2));
            }
#pragma unroll
            for (int p = 0; p < 4; ++p) {
                const unsigned int sel = (chunk >> (p * 2 + half)) & 1u;
                const unsigned int msk = 0u - sel;     // 0 or ~0
                a0 = pkmax_u16(a0, kv[p].x & msk);
                a1 = pkmax_u16(a1, kv[p].y & msk);
                a2 = pkmax_u16(a2, kv[p].z & msk);
                a3 = pkmax_u16(a3, kv[p].w & msk);
            }
        }
    }

    // combine pixel-halves (lane i <-> i+32 hold same channels)
    a0 = pkmax_u16(a0, (unsigned int)__shfl_xor((int)a0, 32, 64));
    a1 = pkmax_u16(a1, (unsigned int)__shfl_xor((int)a1, 32, 64));
    a2 = pkmax_u16(a2, (unsigned int)__shfl_xor((int)a2, 32, 64));
    a3 = pkmax_u16(a3, (unsigned int)__shfl_xor((int)a3, 32, 64));

    if (half == 0) {
        const unsigned int acc[4] = {a0, a1, a2, a3};
        float* o = out + ((size_t)k * CC + (size_t)c4 * 2) * NBIN + ph * P + pw;
#pragma unroll
        for (int j = 0; j < 8; ++j) {
            const unsigned int d = acc[j >> 1];
            const unsigned int key = (j & 1) ? (d >> 16) : (d & 0xFFFFu);
            float r;
            if (key == 0u) {
                r = 0.0f;                       // empty / fully-masked bin
            } else {
                const unsigned int bbits =
                    (key & 0x8000u) ? (key ^ 0x8000u) : (~key & 0xFFFFu);
                r = __uint_as_float(bbits << 16);
            }
            o[(size_t)j * NBIN] = r;
        }
    }
}

// ---------- Fallback (NCHW direct, correctness-only path) ----------
__global__ __launch_bounds__(256) void ROIPool_nchw_kernel(
    const float* __restrict__ inputs, const float* __restrict__ rois,
    const float* __restrict__ masks, float* __restrict__ out)
{
    const int k  = blockIdx.x;
    const int ph = blockIdx.y;
    const int c  = threadIdx.x;

    const float* roi = rois + k * 5;
    const int b  = (int)roi[0];
    const int sw = (int)rintf(roi[1] * SCALE);
    const int sh = (int)rintf(roi[2] * SCALE);
    const int ew = (int)rintf(roi[3] * SCALE);
    const int eh = (int)rintf(roi[4] * SCALE);
    const int roi_w = max(ew - sw + 1, 1);
    const int roi_h = max(eh - sh + 1, 1);

    const int hs = min(max((ph * roi_h) / P + sh, 0), HH);
    const int he = min(max(((ph + 1) * roi_h + P - 1) / P + sh, 0), HH);

    int wsb[P], web[P];
#pragma unroll
    for (int pw = 0; pw < P; ++pw) {
        wsb[pw] = min(max((pw * roi_w) / P + sw, 0), WW);
        web[pw] = min(max(((pw + 1) * roi_w + P - 1) / P + sw, 0), WW);
    }

    const float* f = inputs + ((size_t)b * CC + c) * (HH * WW);
    const float* m = masks  + (size_t)k * (HH * WW);

    float vmax[P];
#pragma unroll
    for (int pw = 0; pw < P; ++pw) vmax[pw] = -INFINITY;

    for (int h = hs; h < he; ++h) {
        const float* frow = f + h * WW;
        const float* mrow = m + h * WW;
#pragma unroll
        for (int pw = 0; pw < P; ++pw) {
            float v = vmax[pw];
            for (int w = wsb[pw]; w < web[pw]; ++w)
                if (mrow[w] > 0.5f) v = fmaxf(v, frow[w]);
            vmax[pw] = v;
        }
    }

    float* o = out + (((size_t)k * CC + c) * P + ph) * P;
#pragma unroll
    for (int pw = 0; pw < P; ++pw) {
        const float v = vmax[pw];
        o[pw] = isinf(v) ? 0.0f : v;
    }
}

extern "C" void kernel_launch(void* const* d_in, const int* in_sizes, int n_in,
                              void* d_out, int out_size, void* d_ws, size_t ws_size,
                              hipStream_t stream) {
    const float* inputs = (const float*)d_in[0];
    const float* rois   = (const float*)d_in[1];
    const float* masks  = (const float*)d_in[2];
    float* out = (float*)d_out;

    const size_t keys_bytes  = (size_t)BB * CC * HH * WW * sizeof(unsigned short); // 32 MiB
    const size_t mbits_bytes = (size_t)KK * HH * 2 * sizeof(unsigned long long);   // 1 MiB

    if (ws_size >= keys_bytes + mbits_bytes) {
        unsigned short* fT = (unsigned short*)d_ws;
        unsigned long long* mb = (unsigned long long*)((char*)d_ws + keys_bytes);
        {
            dim3 grid((HH * WW) / 64, CC / 64, BB);
            dim3 block(64, 16);
            transpose_cvt<<<grid, block, 0, stream>>>(inputs, fT);
        }
        {
            dim3 grid((KK * HH) / 4);
            dim3 block(256);
            mask_bits<<<grid, block, 0, stream>>>(masks, mb);
        }
        {
            dim3 grid(KK * GPB);
            dim3 block(256);
            pool_key<<<grid, block, 0, stream>>>(fT, rois, mb, out);
        }
    } else {
        dim3 grid(KK, P);
        dim3 block(CC);
        ROIPool_nchw_kernel<<<grid, block, 0, stream>>>(inputs, rois, masks, out);
    }
}